// Round 4
// baseline (1638.591 us; speedup 1.0000x reference)
//
#include <hip/hip_runtime.h>

// VQ-VAE quantize: N=8192 rows (dim 512) vs M=8192 codes, fp32 semantics.
// bf16 hi/lo 3-pass MFMA distance GEMM with counted-vmcnt double-buffer
// pipeline; privatized (atomic-free) EMA scatter; coalesced gather.

constexpr int N = 8192;
constexpr int K = 512;
constexpr int M = 8192;

typedef unsigned short ushortT;
typedef __attribute__((ext_vector_type(8))) short s8v;   // 8 bf16 (4 VGPR)
typedef __attribute__((ext_vector_type(4))) float f4v;   // MFMA acc

__device__ __forceinline__ ushortT f2bf(float x) {
    unsigned u = __float_as_uint(x);
    unsigned r = (u + 0x7FFFu + ((u >> 16) & 1u)) >> 16;
    return (ushortT)r;
}
__device__ __forceinline__ float bf2f(ushortT h) {
    return __uint_as_float(((unsigned)h) << 16);
}

typedef const __attribute__((address_space(1))) unsigned gau;
typedef __attribute__((address_space(3))) unsigned lau;
__device__ __forceinline__ void gl16(const void* g, void* l) {
    __builtin_amdgcn_global_load_lds((gau*)g, (lau*)l, 16, 0, 0);
}

__device__ __forceinline__ void top2ins(float& av, int& ai, float& bv, int& bi,
                                        float cv, int ci) {
    if (cv < av || (cv == av && ci < ai)) {
        bv = av; bi = ai; av = cv; ai = ci;
    } else if (cv < bv || (cv == bv && ci < bi)) {
        bv = cv; bi = ci;
    }
}

// ---------- prep: f -> Fh,Fl bf16 [8192][512] ----------
__global__ void k_prepF(const float* __restrict__ f, ushortT* __restrict__ Fh,
                        ushortT* __restrict__ Fl) {
    size_t i8 = ((size_t)blockIdx.x * 256 + threadIdx.x) * 8;
    float4 x0 = *(const float4*)&f[i8];
    float4 x1 = *(const float4*)&f[i8 + 4];
    float xs[8] = {x0.x, x0.y, x0.z, x0.w, x1.x, x1.y, x1.z, x1.w};
    union { s8v v; ushortT u[8]; } h, lo;
#pragma unroll
    for (int j = 0; j < 8; ++j) {
        ushortT hh = f2bf(xs[j]);
        h.u[j] = hh;
        lo.u[j] = f2bf(xs[j] - bf2f(hh));
    }
    *(s8v*)&Fh[i8] = h.v;
    *(s8v*)&Fl[i8] = lo.v;
}

// ---------- prep: E [512][8192] -> EhT,ElT bf16 [8192][512] (transpose) ----------
__global__ __launch_bounds__(256) void k_prepE(const float* __restrict__ E,
                                               ushortT* __restrict__ EhT,
                                               ushortT* __restrict__ ElT) {
    __shared__ float tile[64][65];
    int jb = blockIdx.x & 127, kb = blockIdx.x >> 7;   // 128 x 8 blocks
    int t = threadIdx.x;
    int jj = t & 63, kk0 = t >> 6;
    int j0 = jb * 64, k0 = kb * 64;
#pragma unroll
    for (int it = 0; it < 16; ++it) {
        int kk = it * 4 + kk0;
        tile[kk][jj] = E[(size_t)(k0 + kk) * M + j0 + jj];
    }
    __syncthreads();
    int r = t >> 2, ks = (t & 3) * 16;
    union { s8v v[2]; ushortT u[16]; } h, lo;
#pragma unroll
    for (int i = 0; i < 16; ++i) {
        float x = tile[ks + i][r];
        ushortT hh = f2bf(x);
        h.u[i] = hh;
        lo.u[i] = f2bf(x - bf2f(hh));
    }
    size_t o = (size_t)(j0 + r) * K + k0 + ks;
    *(s8v*)&EhT[o] = h.v[0];
    *(s8v*)&EhT[o + 8] = h.v[1];
    *(s8v*)&ElT[o] = lo.v[0];
    *(s8v*)&ElT[o + 8] = lo.v[1];
}

// ---------- c[j] = ||E_j||^2, deterministic fixed-order partials ----------
__global__ void k_cnorm(const float* __restrict__ E, float* __restrict__ pc) {
    int t = threadIdx.x;
    int jb = blockIdx.x & 31, kc = blockIdx.x >> 5;   // 32 x 8 blocks
    int j = jb * 256 + t;
    float s = 0.f;
#pragma unroll 8
    for (int k2 = 0; k2 < 64; ++k2) {
        float e = E[(size_t)(kc * 64 + k2) * M + j];
        s = fmaf(e, e, s);
    }
    pc[(size_t)kc * M + j] = s;
}

__global__ void k_cfin(const float* __restrict__ pc, float* __restrict__ c,
                       float* __restrict__ counts, float* __restrict__ o_diff) {
    int j = blockIdx.x * 256 + threadIdx.x;
    float s = 0.f;
#pragma unroll
    for (int kc = 0; kc < 8; ++kc) s += pc[(size_t)kc * M + j];
    c[j] = s;
    counts[j] = 0.f;
    if (j == 0) o_diff[0] = 0.f;
}

// ---------- main: counted-vmcnt pipelined 3-pass bf16 MFMA + top-2 argmin ----------
__global__ __launch_bounds__(256, 2) void k_score(
    const ushortT* __restrict__ Fh, const ushortT* __restrict__ Fl,
    const ushortT* __restrict__ Eh, const ushortT* __restrict__ El,
    const float* __restrict__ cE,
    float* __restrict__ pval, int* __restrict__ pidx) {
    __shared__ alignas(16) ushortT bHs[2][4096];   // 16 KB (B-hi dbuf)
    __shared__ alignas(16) ushortT bLs[2][4096];   // 16 KB (B-lo dbuf)
    __shared__ float rv[512];
    __shared__ int   ri[512];

    int bid = blockIdx.x;                       // 4096 blocks
    int wgs = (bid & 7) * 512 + (bid >> 3);     // XCD-contiguous chunks (bijective)
    int rb = (wgs >> 9) * 8 + (wgs & 7);        // 64 row blocks
    int cb = (wgs & 511) >> 3;                  // 64 col blocks
    int rowBase = rb * 128, colBase = cb * 128;
    int tid = threadIdx.x;
    int w = tid >> 6, l = tid & 63;
    int wr = w >> 1, wc = w & 1;
    int l15 = l & 15, g4 = l >> 4;

    // B staging: wave w stages tile rows [w*32, w*32+32), lane l -> row w*32+(l>>2), chunk (l&3)
    const ushortT* srcBh = Eh + (size_t)(colBase + w * 32 + (l >> 2)) * K + (l & 3) * 8;
    const ushortT* srcBl = El + (size_t)(colBase + w * 32 + (l >> 2)) * K + (l & 3) * 8;
    int ldsW = w * 1024;   // ushort idx of wave's staging base

    // A fragments: direct global->reg, lane row = rowBase + wr*64 + m*16 + l15
    const ushortT* srcAh = Fh + (size_t)(rowBase + wr * 64 + l15) * K + g4 * 8;
    const ushortT* srcAl = Fl + (size_t)(rowBase + wr * 64 + l15) * K + g4 * 8;

    f4v acc[4][4];
#pragma unroll
    for (int m = 0; m < 4; ++m)
#pragma unroll
        for (int n = 0; n < 4; ++n) acc[m][n] = (f4v){0.f, 0.f, 0.f, 0.f};

    s8v ahA[4], alA[4], ahB[4], alB[4];

#define STAGE_B(p, t)                                                   \
    do {                                                                \
        size_t ko_ = (size_t)(t) * 32;                                  \
        gl16(srcBh + ko_,          &bHs[p][ldsW]);                      \
        gl16(srcBh + 16 * K + ko_, &bHs[p][ldsW + 512]);                \
        gl16(srcBl + ko_,          &bLs[p][ldsW]);                      \
        gl16(srcBl + 16 * K + ko_, &bLs[p][ldsW + 512]);                \
    } while (0)

#define LOAD_A(ah_, al_, t)                                             \
    do {                                                                \
        size_t ko_ = (size_t)(t) * 32;                                  \
        _Pragma("unroll")                                               \
        for (int m_ = 0; m_ < 4; ++m_) {                                \
            ah_[m_] = *(const s8v*)(srcAh + (size_t)m_ * 16 * K + ko_); \
            al_[m_] = *(const s8v*)(srcAl + (size_t)m_ * 16 * K + ko_); \
        }                                                               \
    } while (0)

#define KSTEP(p, t, aCurH, aCurL, aNxtH, aNxtL)                             \
    do {                                                                    \
        asm volatile("s_waitcnt vmcnt(4)" ::: "memory");                    \
        __builtin_amdgcn_s_barrier();                                       \
        s8v bh[4], bl[4];                                                   \
        _Pragma("unroll")                                                   \
        for (int n_ = 0; n_ < 4; ++n_) {                                    \
            int o_ = (wc * 64 + n_ * 16 + l15) * 32 + g4 * 8;               \
            bh[n_] = *(const s8v*)&bHs[p][o_];                              \
            bl[n_] = *(const s8v*)&bLs[p][o_];                              \
        }                                                                   \
        asm volatile("s_waitcnt lgkmcnt(0)" ::: "memory");                  \
        __builtin_amdgcn_s_barrier();                                       \
        if ((t) + 1 < 16) LOAD_A(aNxtH, aNxtL, (t) + 1);                    \
        if ((t) + 2 < 16) STAGE_B(p, (t) + 2);                              \
        _Pragma("unroll")                                                   \
        for (int m_ = 0; m_ < 4; ++m_)                                      \
            _Pragma("unroll")                                               \
            for (int n_ = 0; n_ < 4; ++n_) {                                \
                acc[m_][n_] = __builtin_amdgcn_mfma_f32_16x16x32_bf16(      \
                    aCurH[m_], bh[n_], acc[m_][n_], 0, 0, 0);               \
                acc[m_][n_] = __builtin_amdgcn_mfma_f32_16x16x32_bf16(      \
                    aCurH[m_], bl[n_], acc[m_][n_], 0, 0, 0);               \
                acc[m_][n_] = __builtin_amdgcn_mfma_f32_16x16x32_bf16(      \
                    aCurL[m_], bh[n_], acc[m_][n_], 0, 0, 0);               \
            }                                                               \
    } while (0)

    // prologue: B(0)->buf0, A(0)->setA, B(1)->buf1  (issue order matters for vmcnt)
    STAGE_B(0, 0);
    LOAD_A(ahA, alA, 0);
    STAGE_B(1, 1);

    for (int t = 0; t < 16; t += 2) {
        KSTEP(0, t,     ahA, alA, ahB, alB);
        KSTEP(1, t + 1, ahB, alB, ahA, alA);
    }

    // epilogue: d = c[j] - 2*acc ; per-row top-2 within this 128-col split
    float cj[4];
#pragma unroll
    for (int n = 0; n < 4; ++n) cj[n] = cE[colBase + wc * 64 + n * 16 + l15];
    __syncthreads();
#pragma unroll
    for (int m = 0; m < 4; ++m)
#pragma unroll
        for (int q = 0; q < 4; ++q) {
            float av = 3.4e38f, bv2 = 3.4e38f;
            int ai = 0x7fffffff, bi2 = 0x7fffffff;
#pragma unroll
            for (int n = 0; n < 4; ++n) {
                float d = fmaf(-2.f, acc[m][n][q], cj[n]);
                top2ins(av, ai, bv2, bi2, d, colBase + wc * 64 + n * 16 + l15);
            }
            for (int mk = 1; mk < 16; mk <<= 1) {
                float oa = __shfl_xor(av, mk), ob = __shfl_xor(bv2, mk);
                int oia = __shfl_xor(ai, mk), oib = __shfl_xor(bi2, mk);
                top2ins(av, ai, bv2, bi2, oa, oia);
                top2ins(av, ai, bv2, bi2, ob, oib);
            }
            if (l15 == 0) {
                int rowW = wr * 64 + m * 16 + g4 * 4 + q;
                rv[(rowW * 2 + wc) * 2 + 0] = av;
                rv[(rowW * 2 + wc) * 2 + 1] = bv2;
                ri[(rowW * 2 + wc) * 2 + 0] = ai;
                ri[(rowW * 2 + wc) * 2 + 1] = bi2;
            }
        }
    __syncthreads();
    if (tid < 128) {
        float av = rv[(tid * 2 + 0) * 2 + 0], bv2 = rv[(tid * 2 + 0) * 2 + 1];
        int ai = ri[(tid * 2 + 0) * 2 + 0], bi2 = ri[(tid * 2 + 0) * 2 + 1];
        top2ins(av, ai, bv2, bi2, rv[(tid * 2 + 1) * 2 + 0], ri[(tid * 2 + 1) * 2 + 0]);
        top2ins(av, ai, bv2, bi2, rv[(tid * 2 + 1) * 2 + 1], ri[(tid * 2 + 1) * 2 + 1]);
        size_t o = ((size_t)cb * N + rowBase + tid) * 2;   // [cb][row][slot]
        pval[o] = av; pval[o + 1] = bv2;
        pidx[o] = ai; pidx[o + 1] = bi2;
    }
#undef KSTEP
#undef LOAD_A
#undef STAGE_B
}

// ---------- combine: re-rank near-min candidates with hi+lo reconstruction ----------
__global__ __launch_bounds__(256) void k_combine(
    const float* __restrict__ pval, const int* __restrict__ pidx,
    const float* __restrict__ f,
    const ushortT* __restrict__ EhT, const ushortT* __restrict__ ElT,
    const float* __restrict__ cE,
    int* __restrict__ indws, float* __restrict__ o_ind, float* __restrict__ counts) {
    int w = threadIdx.x >> 6, l = threadIdx.x & 63;
    int row = blockIdx.x * 4 + w;
    size_t base = ((size_t)l * N + row) * 2;   // lane l owns cb = l
    float v0 = pval[base], v1 = pval[base + 1];
    int i0 = pidx[base], i1 = pidx[base + 1];
    float bv = v0; int bi = i0;
    if (v1 < bv || (v1 == bv && i1 < bi)) { bv = v1; bi = i1; }
    for (int m = 1; m < 64; m <<= 1) {
        float ov = __shfl_xor(bv, m);
        int oi = __shfl_xor(bi, m);
        if (ov < bv || (ov == bv && oi < bi)) { bv = ov; bi = oi; }
    }
    float thr = bv + 0.02f;
    float bestd = 3.4e38f; int bestj = 0x7fffffff;
    float4 fa = *(const float4*)&f[(size_t)row * K + l * 8];
    float4 fb = *(const float4*)&f[(size_t)row * K + l * 8 + 4];
    float fx[8] = {fa.x, fa.y, fa.z, fa.w, fb.x, fb.y, fb.z, fb.w};
#pragma unroll
    for (int s = 0; s < 2; ++s) {
        float v = s ? v1 : v0;
        int ij = s ? i1 : i0;
        unsigned long long mask = __ballot(v <= thr);
        while (mask) {
            int b = __ffsll((unsigned long long)mask) - 1;
            mask &= mask - 1;
            int j = __shfl(ij, b);
            s8v hv = *(const s8v*)(EhT + (size_t)j * K + l * 8);
            s8v lv = *(const s8v*)(ElT + (size_t)j * K + l * 8);
            float a = 0.f;
#pragma unroll
            for (int q = 0; q < 8; ++q)
                a = fmaf(fx[q], bf2f((ushortT)hv[q]) + bf2f((ushortT)lv[q]), a);
            for (int m = 1; m < 64; m <<= 1) a += __shfl_xor(a, m);
            float d = cE[j] - 2.f * a;
            if (d < bestd || (d == bestd && j < bestj)) { bestd = d; bestj = j; }
        }
    }
    if (l == 0) {
        indws[row] = bestj;
        o_ind[row] = (float)bestj;
        atomicAdd(&counts[bestj], 1.0f);
    }
}

// ---------- gather quantize + diff (coalesced EhT/ElT rows) ----------
__global__ __launch_bounds__(64) void k_gather(
    const float* __restrict__ f,
    const ushortT* __restrict__ EhT, const ushortT* __restrict__ ElT,
    const int* __restrict__ indws, float* __restrict__ o_q,
    float* __restrict__ o_diff) {
    int row = blockIdx.x;
    int t = threadIdx.x;   // 64 threads, 8 elems each
    int j = indws[row];
    s8v hv = *(const s8v*)(EhT + (size_t)j * K + t * 8);
    s8v lv = *(const s8v*)(ElT + (size_t)j * K + t * 8);
    float4 x0 = *(const float4*)&f[(size_t)row * K + t * 8];
    float4 x1 = *(const float4*)&f[(size_t)row * K + t * 8 + 4];
    float xs[8] = {x0.x, x0.y, x0.z, x0.w, x1.x, x1.y, x1.z, x1.w};
    float os[8];
    float local = 0.f;
#pragma unroll
    for (int q = 0; q < 8; ++q) {
        float qv = bf2f((ushortT)hv[q]) + bf2f((ushortT)lv[q]);
        float d = qv - xs[q];
        os[q] = xs[q] + d;
        local = fmaf(d, d, local);
    }
    float4 o0 = {os[0], os[1], os[2], os[3]};
    float4 o1 = {os[4], os[5], os[6], os[7]};
    *(float4*)&o_q[(size_t)row * K + t * 8] = o0;
    *(float4*)&o_q[(size_t)row * K + t * 8 + 4] = o1;
#pragma unroll
    for (int off = 32; off; off >>= 1) local += __shfl_down(local, off);
    if (t == 0) atomicAdd(o_diff, local * (1.0f / 4194304.0f));
}

// ---------- privatized EMA: o_avg = 0.99*ea + 0.01*segment_sum (no atomics) ----------
__global__ __launch_bounds__(256) void k_ema(
    const float* __restrict__ f, const int* __restrict__ indws,
    const float* __restrict__ ea, float* __restrict__ o_avg) {
    __shared__ float acc[512 * 32];    // [d][c] 64 KB
    __shared__ int indL[1024];
    int b = blockIdx.x, t = threadIdx.x;
    for (int i = t; i < 512 * 32; i += 256) acc[i] = 0.f;
    for (int r0 = 0; r0 < N; r0 += 1024) {
        __syncthreads();
#pragma unroll
        for (int i = 0; i < 4; ++i) indL[t + i * 256] = indws[r0 + t + i * 256];
        __syncthreads();
        for (int rr = 0; rr < 1024; ++rr) {
            int j = indL[rr];
            if ((j >> 5) == b) {
                int c = j & 31;
                size_t fb = (size_t)(r0 + rr) * K + t;
                acc[t * 32 + c] += f[fb];
                acc[(t + 256) * 32 + c] += f[fb + 256];
            }
        }
    }
    __syncthreads();
    for (int i = t; i < 512 * 32; i += 256) {
        int d = i >> 5, c = i & 31;
        size_t o = (size_t)d * M + b * 32 + c;
        o_avg[o] = 0.99f * ea[o] + 0.01f * acc[i];
    }
}

// ---------- new_cluster_size, n, cs ----------
__global__ __launch_bounds__(256) void k_cs(const float* __restrict__ cs_in,
                                            const float* __restrict__ counts,
                                            float* __restrict__ o_ncs,
                                            float* __restrict__ csr) {
    int tid = threadIdx.x;
    float myncs[32];
    float loc = 0.f;
#pragma unroll 32
    for (int i = 0; i < 32; ++i) {
        int j = i * 256 + tid;
        float v = 0.99f * cs_in[j] + 0.01f * counts[j];
        myncs[i] = v;
        o_ncs[j] = v;
        loc += v;
    }
#pragma unroll
    for (int off = 32; off; off >>= 1) loc += __shfl_down(loc, off);
    __shared__ float wsum[4];
    __shared__ float nsh;
    if ((tid & 63) == 0) wsum[tid >> 6] = loc;
    __syncthreads();
    if (tid == 0) nsh = wsum[0] + wsum[1] + wsum[2] + wsum[3];
    __syncthreads();
    float n = nsh;
#pragma unroll 32
    for (int i = 0; i < 32; ++i) {
        int j = i * 256 + tid;
        csr[j] = (myncs[i] + 1e-5f) / (n + 8192.0f * 1e-5f) * n;
    }
}

// ---------- new_embed = new_embed_avg / cs ----------
__global__ void k_div(const float* __restrict__ avg, const float* __restrict__ csr,
                      float* __restrict__ o_ne) {
    size_t idx = (size_t)blockIdx.x * 256 + threadIdx.x;
    size_t el = idx * 4;
    float4 a = *(const float4*)&avg[el];
    int j = (int)(el & (size_t)(M - 1));
    float4 cc = *(const float4*)&csr[j];
    float4 r;
    r.x = a.x / cc.x; r.y = a.y / cc.y; r.z = a.z / cc.z; r.w = a.w / cc.w;
    *(float4*)&o_ne[el] = r;
}

extern "C" void kernel_launch(void* const* d_in, const int* in_sizes, int n_in,
                              void* d_out, int out_size, void* d_ws, size_t ws_size,
                              hipStream_t stream) {
    const float* f     = (const float*)d_in[0];
    const float* E     = (const float*)d_in[1];
    const float* cs_in = (const float*)d_in[2];
    const float* ea    = (const float*)d_in[3];

    float* out = (float*)d_out;
    float* o_q    = out;                   // 4194304
    float* o_diff = out + 4194304;         // 1
    float* o_ind  = out + 4194305;         // 8192
    float* o_ne   = out + 4202497;         // 4194304
    float* o_ncs  = out + 8396801;         // 8192
    float* o_avg  = out + 8404993;         // 4194304

    // overlays (lifetimes audited):
    //   o_q  region: Fh,Fl   (16 MB) — dead before k_gather writes o_q
    //   o_ne region: EhT,ElT (16 MB) — read by combine/gather; overwritten only by k_div
    //   o_avg region: pval,pidx (8.4 MB) — dead before k_ema writes o_avg
    ushortT* Fh  = (ushortT*)o_q;
    ushortT* Fl  = Fh + (size_t)N * K;
    ushortT* EhT = (ushortT*)o_ne;
    ushortT* ElT = EhT + (size_t)M * K;
    float*   pval = o_avg;                       // [64][8192][2] floats
    int*     pidx = (int*)(o_avg + 1048576);     // [64][8192][2] ints

    float* wsf    = (float*)d_ws;
    float* c      = wsf;                   // 8192
    float* counts = wsf + 8192;            // 8192
    float* csr    = wsf + 16384;           // 8192
    int*   indws  = (int*)(wsf + 24576);   // 8192
    float* pc     = wsf + 32768;           // 8*8192

    k_prepF  <<<2048, 256, 0, stream>>>(f, Fh, Fl);
    k_prepE  <<<1024, 256, 0, stream>>>(E, EhT, ElT);
    k_cnorm  <<<256, 256, 0, stream>>>(E, pc);
    k_cfin   <<<32, 256, 0, stream>>>(pc, c, counts, o_diff);
    k_score  <<<4096, 256, 0, stream>>>(Fh, Fl, EhT, ElT, c, pval, pidx);
    k_combine<<<2048, 256, 0, stream>>>(pval, pidx, f, EhT, ElT, c, indws, o_ind, counts);
    k_gather <<<N, 64, 0, stream>>>(f, EhT, ElT, indws, o_q, o_diff);   // frees Fh/Fl region
    k_ema    <<<256, 256, 0, stream>>>(f, indws, ea, o_avg);            // frees pval/pidx
    k_cs     <<<1, 256, 0, stream>>>(cs_in, counts, o_ncs, csr);
    k_div    <<<4096, 256, 0, stream>>>(o_avg, csr, o_ne);              // overwrites EhT/ElT
}

// Round 5
// 802.835 us; speedup vs baseline: 2.0410x; 2.0410x over previous
//
#include <hip/hip_runtime.h>

// VQ-VAE quantize: N=8192 rows (dim 512) vs M=8192 codes, fp32 semantics.
// Single-pass bf16 MFMA screening GEMM (m97 structure) + exact fp32 re-rank
// (hi/lo bf16 reconstruction, threshold 1.0) + queue-privatized EMA scatter.

constexpr int N = 8192;
constexpr int K = 512;
constexpr int M = 8192;

typedef unsigned short ushortT;
typedef __attribute__((ext_vector_type(8))) short s8v;   // 8 bf16 (4 VGPR)
typedef __attribute__((ext_vector_type(4))) float f4v;   // MFMA acc

__device__ __forceinline__ ushortT f2bf(float x) {
    unsigned u = __float_as_uint(x);
    unsigned r = (u + 0x7FFFu + ((u >> 16) & 1u)) >> 16;
    return (ushortT)r;
}
__device__ __forceinline__ float bf2f(ushortT h) {
    return __uint_as_float(((unsigned)h) << 16);
}

typedef const __attribute__((address_space(1))) unsigned gau;
typedef __attribute__((address_space(3))) unsigned lau;
__device__ __forceinline__ void gl16(const void* g, void* l) {
    __builtin_amdgcn_global_load_lds((gau*)g, (lau*)l, 16, 0, 0);
}

__device__ __forceinline__ void top2ins(float& av, int& ai, float& bv, int& bi,
                                        float cv, int ci) {
    if (cv < av || (cv == av && ci < ai)) {
        bv = av; bi = ai; av = cv; ai = ci;
    } else if (cv < bv || (cv == bv && ci < bi)) {
        bv = cv; bi = ci;
    }
}

// ---------- prep: f -> Fh bf16 [8192][512] (hi only; screening operand) ----------
__global__ void k_prepF(const float* __restrict__ f, ushortT* __restrict__ Fh) {
    size_t i8 = ((size_t)blockIdx.x * 256 + threadIdx.x) * 8;
    float4 x0 = *(const float4*)&f[i8];
    float4 x1 = *(const float4*)&f[i8 + 4];
    float xs[8] = {x0.x, x0.y, x0.z, x0.w, x1.x, x1.y, x1.z, x1.w};
    union { s8v v; ushortT u[8]; } h;
#pragma unroll
    for (int j = 0; j < 8; ++j) h.u[j] = f2bf(xs[j]);
    *(s8v*)&Fh[i8] = h.v;
}

// ---------- prep: E [512][8192] -> EhT,ElT bf16 [8192][512] (transpose) ----------
__global__ __launch_bounds__(256) void k_prepE(const float* __restrict__ E,
                                               ushortT* __restrict__ EhT,
                                               ushortT* __restrict__ ElT) {
    __shared__ float tile[64][65];
    int jb = blockIdx.x & 127, kb = blockIdx.x >> 7;   // 128 x 8 blocks
    int t = threadIdx.x;
    int jj = t & 63, kk0 = t >> 6;
    int j0 = jb * 64, k0 = kb * 64;
#pragma unroll
    for (int it = 0; it < 16; ++it) {
        int kk = it * 4 + kk0;
        tile[kk][jj] = E[(size_t)(k0 + kk) * M + j0 + jj];
    }
    __syncthreads();
    int r = t >> 2, ks = (t & 3) * 16;
    union { s8v v[2]; ushortT u[16]; } h, lo;
#pragma unroll
    for (int i = 0; i < 16; ++i) {
        float x = tile[ks + i][r];
        ushortT hh = f2bf(x);
        h.u[i] = hh;
        lo.u[i] = f2bf(x - bf2f(hh));
    }
    size_t o = (size_t)(j0 + r) * K + k0 + ks;
    *(s8v*)&EhT[o] = h.v[0];
    *(s8v*)&EhT[o + 8] = h.v[1];
    *(s8v*)&ElT[o] = lo.v[0];
    *(s8v*)&ElT[o + 8] = lo.v[1];
}

// ---------- c[j] = ||E_j||^2, deterministic fixed-order partials ----------
__global__ void k_cnorm(const float* __restrict__ E, float* __restrict__ pc) {
    int t = threadIdx.x;
    int jb = blockIdx.x & 31, kc = blockIdx.x >> 5;   // 32 x 8 blocks
    int j = jb * 256 + t;
    float s = 0.f;
#pragma unroll 8
    for (int k2 = 0; k2 < 64; ++k2) {
        float e = E[(size_t)(kc * 64 + k2) * M + j];
        s = fmaf(e, e, s);
    }
    pc[(size_t)kc * M + j] = s;
}

__global__ void k_cfin(const float* __restrict__ pc, float* __restrict__ c,
                       float* __restrict__ counts, float* __restrict__ o_diff) {
    int j = blockIdx.x * 256 + threadIdx.x;
    float s = 0.f;
#pragma unroll
    for (int kc = 0; kc < 8; ++kc) s += pc[(size_t)kc * M + j];
    c[j] = s;
    counts[j] = 0.f;
    if (j == 0) o_diff[0] = 0.f;
}

// ---------- main: single-pass bf16 MFMA screening + per-split top-2 ----------
__global__ __launch_bounds__(256, 4) void k_score(
    const ushortT* __restrict__ Fh, const ushortT* __restrict__ Eh,
    const float* __restrict__ cE,
    float* __restrict__ pval, int* __restrict__ pidx) {
    __shared__ alignas(16) ushortT aH[4096], bH[4096];   // 8 KB + 8 KB
    __shared__ float rv[512];
    __shared__ int   ri[512];

    int bid = blockIdx.x;                       // 4096 blocks
    int wgs = (bid & 7) * 512 + (bid >> 3);     // XCD-contiguous chunks (bijective)
    int rb = (wgs >> 9) * 8 + (wgs & 7);        // 64 row blocks
    int cb = (wgs & 511) >> 3;                  // 64 col blocks
    int rowBase = rb * 128, colBase = cb * 128;
    int tid = threadIdx.x;
    int w = tid >> 6, l = tid & 63;
    int wr = w >> 1, wc = w & 1;
    int l15 = l & 15, g4 = l >> 4;

    // staging: wave w stages tile rows [w*32, w*32+32); lane l -> row w*32+(l>>2), chunk l&3
    const ushortT* srcA = Fh + (size_t)(rowBase + w * 32 + (l >> 2)) * K + (l & 3) * 8;
    const ushortT* srcB = Eh + (size_t)(colBase + w * 32 + (l >> 2)) * K + (l & 3) * 8;
    int ldsW = w * 1024;   // ushort idx of wave's staging base (linear in lane)

    f4v acc[4][4];
#pragma unroll
    for (int m = 0; m < 4; ++m)
#pragma unroll
        for (int n = 0; n < 4; ++n) acc[m][n] = (f4v){0.f, 0.f, 0.f, 0.f};

    for (int k0 = 0; k0 < K; k0 += 32) {
        __syncthreads();   // protect LDS reuse
        gl16(srcA + k0,          &aH[ldsW]);
        gl16(srcA + 16 * K + k0, &aH[ldsW + 512]);
        gl16(srcB + k0,          &bH[ldsW]);
        gl16(srcB + 16 * K + k0, &bH[ldsW + 512]);
        __syncthreads();   // compiler drains vmcnt before barrier
        s8v ah[4], bh[4];
#pragma unroll
        for (int m = 0; m < 4; ++m)
            ah[m] = *(const s8v*)&aH[(wr * 64 + m * 16 + l15) * 32 + g4 * 8];
#pragma unroll
        for (int n = 0; n < 4; ++n)
            bh[n] = *(const s8v*)&bH[(wc * 64 + n * 16 + l15) * 32 + g4 * 8];
#pragma unroll
        for (int m = 0; m < 4; ++m)
#pragma unroll
            for (int n = 0; n < 4; ++n)
                acc[m][n] = __builtin_amdgcn_mfma_f32_16x16x32_bf16(
                    ah[m], bh[n], acc[m][n], 0, 0, 0);
    }

    // epilogue: d = c[j] - 2*acc ; per-row top-2 within this 128-col split
    float cj[4];
#pragma unroll
    for (int n = 0; n < 4; ++n) cj[n] = cE[colBase + wc * 64 + n * 16 + l15];
    __syncthreads();
#pragma unroll
    for (int m = 0; m < 4; ++m)
#pragma unroll
        for (int q = 0; q < 4; ++q) {
            float av = 3.4e38f, bv2 = 3.4e38f;
            int ai = 0x7fffffff, bi2 = 0x7fffffff;
#pragma unroll
            for (int n = 0; n < 4; ++n) {
                float d = fmaf(-2.f, acc[m][n][q], cj[n]);
                top2ins(av, ai, bv2, bi2, d, colBase + wc * 64 + n * 16 + l15);
            }
            for (int mk = 1; mk < 16; mk <<= 1) {
                float oa = __shfl_xor(av, mk), ob = __shfl_xor(bv2, mk);
                int oia = __shfl_xor(ai, mk), oib = __shfl_xor(bi2, mk);
                top2ins(av, ai, bv2, bi2, oa, oia);
                top2ins(av, ai, bv2, bi2, ob, oib);
            }
            if (l15 == 0) {
                int rowW = wr * 64 + m * 16 + g4 * 4 + q;
                rv[(rowW * 2 + wc) * 2 + 0] = av;
                rv[(rowW * 2 + wc) * 2 + 1] = bv2;
                ri[(rowW * 2 + wc) * 2 + 0] = ai;
                ri[(rowW * 2 + wc) * 2 + 1] = bi2;
            }
        }
    __syncthreads();
    if (tid < 128) {
        float av = rv[(tid * 2 + 0) * 2 + 0], bv2 = rv[(tid * 2 + 0) * 2 + 1];
        int ai = ri[(tid * 2 + 0) * 2 + 0], bi2 = ri[(tid * 2 + 0) * 2 + 1];
        top2ins(av, ai, bv2, bi2, rv[(tid * 2 + 1) * 2 + 0], ri[(tid * 2 + 1) * 2 + 0]);
        top2ins(av, ai, bv2, bi2, rv[(tid * 2 + 1) * 2 + 1], ri[(tid * 2 + 1) * 2 + 1]);
        size_t o = ((size_t)cb * N + rowBase + tid) * 2;   // [cb][row][slot]
        pval[o] = av; pval[o + 1] = bv2;
        pidx[o] = ai; pidx[o + 1] = bi2;
    }
}

// ---------- combine: exact fp32 re-rank (hi+lo recon), thr = min + 1.0 ----------
__global__ __launch_bounds__(256) void k_combine(
    const float* __restrict__ pval, const int* __restrict__ pidx,
    const float* __restrict__ f,
    const ushortT* __restrict__ EhT, const ushortT* __restrict__ ElT,
    const float* __restrict__ cE,
    int* __restrict__ indws, float* __restrict__ o_ind, float* __restrict__ counts) {
    int w = threadIdx.x >> 6, l = threadIdx.x & 63;
    int row = blockIdx.x * 4 + w;
    size_t base = ((size_t)l * N + row) * 2;   // lane l owns cb = l
    float v0 = pval[base], v1 = pval[base + 1];
    int i0 = pidx[base], i1 = pidx[base + 1];
    float bv = v0; int bi = i0;
    if (v1 < bv || (v1 == bv && i1 < bi)) { bv = v1; bi = i1; }
    for (int m = 1; m < 64; m <<= 1) {
        float ov = __shfl_xor(bv, m);
        int oi = __shfl_xor(bi, m);
        if (ov < bv || (ov == bv && oi < bi)) { bv = ov; bi = oi; }
    }
    float thr = bv + 1.0f;   // 14-sigma of single-pass bf16 screening error
    float bestd = 3.4e38f; int bestj = 0x7fffffff;
    float4 fa = *(const float4*)&f[(size_t)row * K + l * 8];
    float4 fb = *(const float4*)&f[(size_t)row * K + l * 8 + 4];
    float fx[8] = {fa.x, fa.y, fa.z, fa.w, fb.x, fb.y, fb.z, fb.w};
#pragma unroll
    for (int s = 0; s < 2; ++s) {
        float v = s ? v1 : v0;
        int ij = s ? i1 : i0;
        unsigned long long mask = __ballot(v <= thr);
        while (mask) {
            int b = __ffsll((unsigned long long)mask) - 1;
            mask &= mask - 1;
            int j = __shfl(ij, b);
            s8v hv = *(const s8v*)(EhT + (size_t)j * K + l * 8);
            s8v lv = *(const s8v*)(ElT + (size_t)j * K + l * 8);
            float a = 0.f;
#pragma unroll
            for (int q = 0; q < 8; ++q)
                a = fmaf(fx[q], bf2f((ushortT)hv[q]) + bf2f((ushortT)lv[q]), a);
            for (int m = 1; m < 64; m <<= 1) a += __shfl_xor(a, m);
            float d = cE[j] - 2.f * a;
            if (d < bestd || (d == bestd && j < bestj)) { bestd = d; bestj = j; }
        }
    }
    if (l == 0) {
        indws[row] = bestj;
        o_ind[row] = (float)bestj;
        atomicAdd(&counts[bestj], 1.0f);
    }
}

// ---------- gather quantize + diff (coalesced EhT/ElT rows) ----------
__global__ __launch_bounds__(64) void k_gather(
    const float* __restrict__ f,
    const ushortT* __restrict__ EhT, const ushortT* __restrict__ ElT,
    const int* __restrict__ indws, float* __restrict__ o_q,
    float* __restrict__ o_diff) {
    int row = blockIdx.x;
    int t = threadIdx.x;   // 64 threads, 8 elems each
    int j = indws[row];
    s8v hv = *(const s8v*)(EhT + (size_t)j * K + t * 8);
    s8v lv = *(const s8v*)(ElT + (size_t)j * K + t * 8);
    float4 x0 = *(const float4*)&f[(size_t)row * K + t * 8];
    float4 x1 = *(const float4*)&f[(size_t)row * K + t * 8 + 4];
    float xs[8] = {x0.x, x0.y, x0.z, x0.w, x1.x, x1.y, x1.z, x1.w};
    float os[8];
    float local = 0.f;
#pragma unroll
    for (int q = 0; q < 8; ++q) {
        float qv = bf2f((ushortT)hv[q]) + bf2f((ushortT)lv[q]);
        float d = qv - xs[q];
        os[q] = xs[q] + d;
        local = fmaf(d, d, local);
    }
    float4 o0 = {os[0], os[1], os[2], os[3]};
    float4 o1 = {os[4], os[5], os[6], os[7]};
    *(float4*)&o_q[(size_t)row * K + t * 8] = o0;
    *(float4*)&o_q[(size_t)row * K + t * 8 + 4] = o1;
#pragma unroll
    for (int off = 32; off; off >>= 1) local += __shfl_down(local, off);
    if (t == 0) atomicAdd(o_diff, local * (1.0f / 4194304.0f));
}

// ---------- EMA: block b owns 32 codes; LDS queue of hit rows; no global atomics ----
__global__ __launch_bounds__(256) void k_ema(
    const float* __restrict__ f, const int* __restrict__ indws,
    const float* __restrict__ ea, float* __restrict__ o_avg) {
    __shared__ float acc[512 * 33];   // [d][c] padded: 67.6 KB, conflict-free
    __shared__ int q[8192];           // packed (row<<5)|c ; worst case all rows
    __shared__ int qn;
    int b = blockIdx.x, t = threadIdx.x;
    for (int i = t; i < 512 * 33; i += 256) acc[i] = 0.f;
    if (t == 0) qn = 0;
    __syncthreads();
    for (int r = t; r < N; r += 256) {          // coalesced scan of indices
        int j = indws[r];
        if ((j >> 5) == b) {
            int s = atomicAdd(&qn, 1);
            q[s] = (r << 5) | (j & 31);
        }
    }
    __syncthreads();
    int nq = qn;
    int s = 0;
    for (; s + 4 <= nq; s += 4) {               // 4-way ILP over queued rows
        int e0 = q[s], e1 = q[s + 1], e2 = q[s + 2], e3 = q[s + 3];
        float a0 = f[(size_t)(e0 >> 5) * K + t],       c0 = f[(size_t)(e0 >> 5) * K + t + 256];
        float a1 = f[(size_t)(e1 >> 5) * K + t],       c1 = f[(size_t)(e1 >> 5) * K + t + 256];
        float a2 = f[(size_t)(e2 >> 5) * K + t],       c2 = f[(size_t)(e2 >> 5) * K + t + 256];
        float a3 = f[(size_t)(e3 >> 5) * K + t],       c3 = f[(size_t)(e3 >> 5) * K + t + 256];
        acc[t * 33 + (e0 & 31)] += a0;         acc[(t + 256) * 33 + (e0 & 31)] += c0;
        acc[t * 33 + (e1 & 31)] += a1;         acc[(t + 256) * 33 + (e1 & 31)] += c1;
        acc[t * 33 + (e2 & 31)] += a2;         acc[(t + 256) * 33 + (e2 & 31)] += c2;
        acc[t * 33 + (e3 & 31)] += a3;         acc[(t + 256) * 33 + (e3 & 31)] += c3;
    }
    for (; s < nq; ++s) {
        int e = q[s];
        float a0 = f[(size_t)(e >> 5) * K + t];
        float c0 = f[(size_t)(e >> 5) * K + t + 256];
        acc[t * 33 + (e & 31)] += a0;
        acc[(t + 256) * 33 + (e & 31)] += c0;
    }
    __syncthreads();
    for (int i = t; i < 512 * 32; i += 256) {   // fused EMA write-out
        int d = i >> 5, c = i & 31;
        size_t o = (size_t)d * M + b * 32 + c;
        o_avg[o] = 0.99f * ea[o] + 0.01f * acc[d * 33 + c];
    }
}

// ---------- new_cluster_size, n, cs ----------
__global__ __launch_bounds__(256) void k_cs(const float* __restrict__ cs_in,
                                            const float* __restrict__ counts,
                                            float* __restrict__ o_ncs,
                                            float* __restrict__ csr) {
    int tid = threadIdx.x;
    float myncs[32];
    float loc = 0.f;
#pragma unroll 32
    for (int i = 0; i < 32; ++i) {
        int j = i * 256 + tid;
        float v = 0.99f * cs_in[j] + 0.01f * counts[j];
        myncs[i] = v;
        o_ncs[j] = v;
        loc += v;
    }
#pragma unroll
    for (int off = 32; off; off >>= 1) loc += __shfl_down(loc, off);
    __shared__ float wsum[4];
    __shared__ float nsh;
    if ((tid & 63) == 0) wsum[tid >> 6] = loc;
    __syncthreads();
    if (tid == 0) nsh = wsum[0] + wsum[1] + wsum[2] + wsum[3];
    __syncthreads();
    float n = nsh;
#pragma unroll 32
    for (int i = 0; i < 32; ++i) {
        int j = i * 256 + tid;
        csr[j] = (myncs[i] + 1e-5f) / (n + 8192.0f * 1e-5f) * n;
    }
}

// ---------- new_embed = new_embed_avg / cs ----------
__global__ void k_div(const float* __restrict__ avg, const float* __restrict__ csr,
                      float* __restrict__ o_ne) {
    size_t idx = (size_t)blockIdx.x * 256 + threadIdx.x;
    size_t el = idx * 4;
    float4 a = *(const float4*)&avg[el];
    int j = (int)(el & (size_t)(M - 1));
    float4 cc = *(const float4*)&csr[j];
    float4 r;
    r.x = a.x / cc.x; r.y = a.y / cc.y; r.z = a.z / cc.z; r.w = a.w / cc.w;
    *(float4*)&o_ne[el] = r;
}

extern "C" void kernel_launch(void* const* d_in, const int* in_sizes, int n_in,
                              void* d_out, int out_size, void* d_ws, size_t ws_size,
                              hipStream_t stream) {
    const float* f     = (const float*)d_in[0];
    const float* E     = (const float*)d_in[1];
    const float* cs_in = (const float*)d_in[2];
    const float* ea    = (const float*)d_in[3];

    float* out = (float*)d_out;
    float* o_q    = out;                   // 4194304
    float* o_diff = out + 4194304;         // 1
    float* o_ind  = out + 4194305;         // 8192
    float* o_ne   = out + 4202497;         // 4194304
    float* o_ncs  = out + 8396801;         // 8192
    float* o_avg  = out + 8404993;         // 4194304

    // overlays (lifetimes audited):
    //   o_q  region: Fh (8 MB) — dead after k_score; k_gather then writes o_q
    //   o_ne region: EhT,ElT (16 MB) — read by score/combine/gather; k_div writes last
    //   o_avg region: pval,pidx (8 MB) — dead after k_combine; k_ema then writes o_avg
    ushortT* Fh  = (ushortT*)o_q;
    ushortT* EhT = (ushortT*)o_ne;
    ushortT* ElT = EhT + (size_t)M * K;
    float*   pval = o_avg;                       // [64][8192][2] floats
    int*     pidx = (int*)(o_avg + 1048576);     // [64][8192][2] ints

    float* wsf    = (float*)d_ws;
    float* c      = wsf;                   // 8192
    float* counts = wsf + 8192;            // 8192
    float* csr    = wsf + 16384;           // 8192
    int*   indws  = (int*)(wsf + 24576);   // 8192
    float* pc     = wsf + 32768;           // 8*8192

    k_prepF  <<<2048, 256, 0, stream>>>(f, Fh);
    k_prepE  <<<1024, 256, 0, stream>>>(E, EhT, ElT);
    k_cnorm  <<<256, 256, 0, stream>>>(E, pc);
    k_cfin   <<<32, 256, 0, stream>>>(pc, c, counts, o_diff);
    k_score  <<<4096, 256, 0, stream>>>(Fh, EhT, c, pval, pidx);
    k_combine<<<2048, 256, 0, stream>>>(pval, pidx, f, EhT, ElT, c, indws, o_ind, counts);
    k_gather <<<N, 64, 0, stream>>>(f, EhT, ElT, indws, o_q, o_diff);   // frees Fh region
    k_ema    <<<256, 256, 0, stream>>>(f, indws, ea, o_avg);            // frees pval/pidx
    k_cs     <<<1, 256, 0, stream>>>(cs_in, counts, o_ncs, csr);
    k_div    <<<4096, 256, 0, stream>>>(o_avg, csr, o_ne);              // overwrites EhT/ElT
}

// Round 6
// 427.578 us; speedup vs baseline: 3.8323x; 1.8776x over previous
//
#include <hip/hip_runtime.h>

// VQ-VAE quantize: N=8192 rows (dim 512) vs M=8192 codes, fp32 semantics.
// Distance GEMM: barrier-free direct-global bf16 MFMA (data is L2-resident;
// no LDS staging) + packed-u64 top-2 epilogue + exact fp32 re-rank.

constexpr int N = 8192;
constexpr int K = 512;
constexpr int M = 8192;

typedef unsigned short ushortT;
typedef unsigned long long u64;
typedef __attribute__((ext_vector_type(8))) short s8v;   // 8 bf16 (4 VGPR)
typedef __attribute__((ext_vector_type(4))) float f4v;   // MFMA acc

__device__ __forceinline__ ushortT f2bf(float x) {
    unsigned u = __float_as_uint(x);
    unsigned r = (u + 0x7FFFu + ((u >> 16) & 1u)) >> 16;
    return (ushortT)r;
}
__device__ __forceinline__ float bf2f(ushortT h) {
    return __uint_as_float(((unsigned)h) << 16);
}

// sortable-float packing: enc(d) monotone in d; low 13 bits = code index.
__device__ __forceinline__ u64 packDI(float d, int col) {
    unsigned u = __float_as_uint(d);
    unsigned e = (u & 0x80000000u) ? ~u : (u | 0x80000000u);
    return ((u64)e << 13) | (unsigned)col;
}
__device__ __forceinline__ float unpackD(u64 p) {
    unsigned e = (unsigned)(p >> 13);
    unsigned u = (e & 0x80000000u) ? (e & 0x7fffffffu) : ~e;
    return __uint_as_float(u);
}
__device__ __forceinline__ void top2u(u64& a, u64& b, u64 c) {
    u64 mn = c < a ? c : a;
    u64 mx = c < a ? a : c;
    a = mn;
    b = mx < b ? mx : b;
}

__device__ __forceinline__ void top2ins(float& av, int& ai, float& bv, int& bi,
                                        float cv, int ci) {
    if (cv < av || (cv == av && ci < ai)) {
        bv = av; bi = ai; av = cv; ai = ci;
    } else if (cv < bv || (cv == bv && ci < bi)) {
        bv = cv; bi = ci;
    }
}

// ---------- prep: f -> Fh bf16 [8192][512] (hi only; screening operand) ----------
__global__ void k_prepF(const float* __restrict__ f, ushortT* __restrict__ Fh) {
    size_t i8 = ((size_t)blockIdx.x * 256 + threadIdx.x) * 8;
    float4 x0 = *(const float4*)&f[i8];
    float4 x1 = *(const float4*)&f[i8 + 4];
    float xs[8] = {x0.x, x0.y, x0.z, x0.w, x1.x, x1.y, x1.z, x1.w};
    union { s8v v; ushortT u[8]; } h;
#pragma unroll
    for (int j = 0; j < 8; ++j) h.u[j] = f2bf(xs[j]);
    *(s8v*)&Fh[i8] = h.v;
}

// ---------- prep: E [512][8192] -> EhT,ElT bf16 [8192][512] (transpose) ----------
__global__ __launch_bounds__(256) void k_prepE(const float* __restrict__ E,
                                               ushortT* __restrict__ EhT,
                                               ushortT* __restrict__ ElT) {
    __shared__ float tile[64][65];
    int jb = blockIdx.x & 127, kb = blockIdx.x >> 7;   // 128 x 8 blocks
    int t = threadIdx.x;
    int jj = t & 63, kk0 = t >> 6;
    int j0 = jb * 64, k0 = kb * 64;
#pragma unroll
    for (int it = 0; it < 16; ++it) {
        int kk = it * 4 + kk0;
        tile[kk][jj] = E[(size_t)(k0 + kk) * M + j0 + jj];
    }
    __syncthreads();
    int r = t >> 2, ks = (t & 3) * 16;
    union { s8v v[2]; ushortT u[16]; } h, lo;
#pragma unroll
    for (int i = 0; i < 16; ++i) {
        float x = tile[ks + i][r];
        ushortT hh = f2bf(x);
        h.u[i] = hh;
        lo.u[i] = f2bf(x - bf2f(hh));
    }
    size_t o = (size_t)(j0 + r) * K + k0 + ks;
    *(s8v*)&EhT[o] = h.v[0];
    *(s8v*)&EhT[o + 8] = h.v[1];
    *(s8v*)&ElT[o] = lo.v[0];
    *(s8v*)&ElT[o + 8] = lo.v[1];
}

// ---------- c[j] = ||E_j||^2, deterministic fixed-order partials ----------
__global__ void k_cnorm(const float* __restrict__ E, float* __restrict__ pc) {
    int t = threadIdx.x;
    int jb = blockIdx.x & 31, kc = blockIdx.x >> 5;   // 32 x 8 blocks
    int j = jb * 256 + t;
    float s = 0.f;
#pragma unroll 8
    for (int k2 = 0; k2 < 64; ++k2) {
        float e = E[(size_t)(kc * 64 + k2) * M + j];
        s = fmaf(e, e, s);
    }
    pc[(size_t)kc * M + j] = s;
}

__global__ void k_cfin(const float* __restrict__ pc, float* __restrict__ c,
                       float* __restrict__ counts, float* __restrict__ o_diff) {
    int j = blockIdx.x * 256 + threadIdx.x;
    float s = 0.f;
#pragma unroll
    for (int kc = 0; kc < 8; ++kc) s += pc[(size_t)kc * M + j];
    c[j] = s;
    counts[j] = 0.f;
    if (j == 0) o_diff[0] = 0.f;
}

// ---------- main: barrier-free direct-global bf16 MFMA + packed top-2 ----------
__global__ __launch_bounds__(256) void k_score(
    const ushortT* __restrict__ Fh, const ushortT* __restrict__ Eh,
    const float* __restrict__ cE,
    float* __restrict__ pval, int* __restrict__ pidx) {
    __shared__ u64 cand[128 * 33];   // [row][32 slots], stride 33 (2-way-safe), 33.8 KB

    int bid = blockIdx.x;                       // 4096 blocks
    int wgs = (bid & 7) * 512 + (bid >> 3);     // XCD-contiguous chunks (bijective)
    int rb = (wgs >> 9) * 8 + (wgs & 7);        // 64 row blocks
    int cb = (wgs & 511) >> 3;                  // 64 col blocks
    int rowBase = rb * 128, colBase = cb * 128;
    int tid = threadIdx.x;
    int w = tid >> 6, l = tid & 63;
    int wr = w >> 1, wc = w & 1;
    int l15 = l & 15, g4 = l >> 4;

    // fragment bases: 4 A-rows and 4 B-rows per lane; k0 folds into imm offset
    const ushortT* A0 = Fh + (size_t)(rowBase + wr * 64 + l15) * K + g4 * 8;
    const ushortT* B0 = Eh + (size_t)(colBase + wc * 64 + l15) * K + g4 * 8;

    f4v acc[4][4];
#pragma unroll
    for (int m = 0; m < 4; ++m)
#pragma unroll
        for (int n = 0; n < 4; ++n) acc[m][n] = (f4v){0.f, 0.f, 0.f, 0.f};

#pragma unroll
    for (int k0 = 0; k0 < K; k0 += 32) {
        s8v a[4], b[4];
#pragma unroll
        for (int m = 0; m < 4; ++m)
            a[m] = *(const s8v*)(A0 + (size_t)m * 16 * K + k0);
#pragma unroll
        for (int n = 0; n < 4; ++n)
            b[n] = *(const s8v*)(B0 + (size_t)n * 16 * K + k0);
#pragma unroll
        for (int m = 0; m < 4; ++m)
#pragma unroll
            for (int n = 0; n < 4; ++n)
                acc[m][n] = __builtin_amdgcn_mfma_f32_16x16x32_bf16(
                    a[m], b[n], acc[m][n], 0, 0, 0);
    }

    // epilogue: d = c[j] - 2*acc ; packed-u64 top-2 per row over this 128-col split
    float cj[4];
#pragma unroll
    for (int n = 0; n < 4; ++n) cj[n] = cE[colBase + wc * 64 + n * 16 + l15];

#pragma unroll
    for (int m = 0; m < 4; ++m)
#pragma unroll
        for (int q = 0; q < 4; ++q) {
            u64 p0 = packDI(fmaf(-2.f, acc[m][0][q], cj[0]), colBase + wc * 64 + l15);
            u64 p1 = packDI(fmaf(-2.f, acc[m][1][q], cj[1]), colBase + wc * 64 + 16 + l15);
            u64 p2 = packDI(fmaf(-2.f, acc[m][2][q], cj[2]), colBase + wc * 64 + 32 + l15);
            u64 p3 = packDI(fmaf(-2.f, acc[m][3][q], cj[3]), colBase + wc * 64 + 48 + l15);
            u64 a_ = p0 < p1 ? p0 : p1;
            u64 b_ = p0 < p1 ? p1 : p0;
            top2u(a_, b_, p2);
            top2u(a_, b_, p3);
            // one butterfly round: fold lanes l15 and l15^8
            u64 oa = __shfl_xor(a_, 8);
            u64 ob = __shfl_xor(b_, 8);
            top2u(a_, b_, oa);
            top2u(a_, b_, ob);
            if (!(l15 & 8)) {
                int row = wr * 64 + m * 16 + g4 * 4 + q;
                int slot = wc * 16 + (l15 & 7) * 2;
                cand[row * 33 + slot]     = a_;
                cand[row * 33 + slot + 1] = b_;
            }
        }
    __syncthreads();
    if (tid < 128) {
        u64 best = cand[tid * 33], second = cand[tid * 33 + 1];   // written ordered
#pragma unroll
        for (int i = 2; i < 32; i += 2) {
            top2u(best, second, cand[tid * 33 + i]);
            top2u(best, second, cand[tid * 33 + i + 1]);
        }
        size_t o = ((size_t)cb * N + rowBase + tid) * 2;   // [cb][row][slot]
        pval[o] = unpackD(best);
        pval[o + 1] = unpackD(second);
        pidx[o] = (int)(best & 0x1fffu);
        pidx[o + 1] = (int)(second & 0x1fffu);
    }
}

// ---------- combine: exact fp32 re-rank (hi+lo recon), thr = min + 1.0 ----------
__global__ __launch_bounds__(256) void k_combine(
    const float* __restrict__ pval, const int* __restrict__ pidx,
    const float* __restrict__ f,
    const ushortT* __restrict__ EhT, const ushortT* __restrict__ ElT,
    const float* __restrict__ cE,
    int* __restrict__ indws, float* __restrict__ o_ind, float* __restrict__ counts) {
    int w = threadIdx.x >> 6, l = threadIdx.x & 63;
    int row = blockIdx.x * 4 + w;
    size_t base = ((size_t)l * N + row) * 2;   // lane l owns cb = l
    float v0 = pval[base], v1 = pval[base + 1];
    int i0 = pidx[base], i1 = pidx[base + 1];
    float bv = v0; int bi = i0;
    if (v1 < bv || (v1 == bv && i1 < bi)) { bv = v1; bi = i1; }
    for (int m = 1; m < 64; m <<= 1) {
        float ov = __shfl_xor(bv, m);
        int oi = __shfl_xor(bi, m);
        if (ov < bv || (ov == bv && oi < bi)) { bv = ov; bi = oi; }
    }
    float thr = bv + 1.0f;   // 14-sigma of single-pass bf16 screening error
    float bestd = 3.4e38f; int bestj = 0x7fffffff;
    float4 fa = *(const float4*)&f[(size_t)row * K + l * 8];
    float4 fb = *(const float4*)&f[(size_t)row * K + l * 8 + 4];
    float fx[8] = {fa.x, fa.y, fa.z, fa.w, fb.x, fb.y, fb.z, fb.w};
#pragma unroll
    for (int s = 0; s < 2; ++s) {
        float v = s ? v1 : v0;
        int ij = s ? i1 : i0;
        unsigned long long mask = __ballot(v <= thr);
        while (mask) {
            int b = __ffsll((unsigned long long)mask) - 1;
            mask &= mask - 1;
            int j = __shfl(ij, b);
            s8v hv = *(const s8v*)(EhT + (size_t)j * K + l * 8);
            s8v lv = *(const s8v*)(ElT + (size_t)j * K + l * 8);
            float a = 0.f;
#pragma unroll
            for (int q = 0; q < 8; ++q)
                a = fmaf(fx[q], bf2f((ushortT)hv[q]) + bf2f((ushortT)lv[q]), a);
            for (int m = 1; m < 64; m <<= 1) a += __shfl_xor(a, m);
            float d = cE[j] - 2.f * a;
            if (d < bestd || (d == bestd && j < bestj)) { bestd = d; bestj = j; }
        }
    }
    if (l == 0) {
        indws[row] = bestj;
        o_ind[row] = (float)bestj;
        atomicAdd(&counts[bestj], 1.0f);
    }
}

// ---------- gather quantize + diff (coalesced EhT/ElT rows) ----------
__global__ __launch_bounds__(64) void k_gather(
    const float* __restrict__ f,
    const ushortT* __restrict__ EhT, const ushortT* __restrict__ ElT,
    const int* __restrict__ indws, float* __restrict__ o_q,
    float* __restrict__ o_diff) {
    int row = blockIdx.x;
    int t = threadIdx.x;   // 64 threads, 8 elems each
    int j = indws[row];
    s8v hv = *(const s8v*)(EhT + (size_t)j * K + t * 8);
    s8v lv = *(const s8v*)(ElT + (size_t)j * K + t * 8);
    float4 x0 = *(const float4*)&f[(size_t)row * K + t * 8];
    float4 x1 = *(const float4*)&f[(size_t)row * K + t * 8 + 4];
    float xs[8] = {x0.x, x0.y, x0.z, x0.w, x1.x, x1.y, x1.z, x1.w};
    float os[8];
    float local = 0.f;
#pragma unroll
    for (int q = 0; q < 8; ++q) {
        float qv = bf2f((ushortT)hv[q]) + bf2f((ushortT)lv[q]);
        float d = qv - xs[q];
        os[q] = xs[q] + d;
        local = fmaf(d, d, local);
    }
    float4 o0 = {os[0], os[1], os[2], os[3]};
    float4 o1 = {os[4], os[5], os[6], os[7]};
    *(float4*)&o_q[(size_t)row * K + t * 8] = o0;
    *(float4*)&o_q[(size_t)row * K + t * 8 + 4] = o1;
#pragma unroll
    for (int off = 32; off; off >>= 1) local += __shfl_down(local, off);
    if (t == 0) atomicAdd(o_diff, local * (1.0f / 4194304.0f));
}

// ---------- EMA: block b owns 32 codes; LDS queue of hit rows; no global atomics ----
__global__ __launch_bounds__(256) void k_ema(
    const float* __restrict__ f, const int* __restrict__ indws,
    const float* __restrict__ ea, float* __restrict__ o_avg) {
    __shared__ float acc[512 * 33];   // [d][c] padded: 67.6 KB, conflict-free
    __shared__ int q[8192];           // packed (row<<5)|c ; worst case all rows
    __shared__ int qn;
    int b = blockIdx.x, t = threadIdx.x;
    for (int i = t; i < 512 * 33; i += 256) acc[i] = 0.f;
    if (t == 0) qn = 0;
    __syncthreads();
    for (int r = t; r < N; r += 256) {          // coalesced scan of indices
        int j = indws[r];
        if ((j >> 5) == b) {
            int s = atomicAdd(&qn, 1);
            q[s] = (r << 5) | (j & 31);
        }
    }
    __syncthreads();
    int nq = qn;
    int s = 0;
    for (; s + 4 <= nq; s += 4) {               // 4-way ILP over queued rows
        int e0 = q[s], e1 = q[s + 1], e2 = q[s + 2], e3 = q[s + 3];
        float a0 = f[(size_t)(e0 >> 5) * K + t],       c0 = f[(size_t)(e0 >> 5) * K + t + 256];
        float a1 = f[(size_t)(e1 >> 5) * K + t],       c1 = f[(size_t)(e1 >> 5) * K + t + 256];
        float a2 = f[(size_t)(e2 >> 5) * K + t],       c2 = f[(size_t)(e2 >> 5) * K + t + 256];
        float a3 = f[(size_t)(e3 >> 5) * K + t],       c3 = f[(size_t)(e3 >> 5) * K + t + 256];
        acc[t * 33 + (e0 & 31)] += a0;         acc[(t + 256) * 33 + (e0 & 31)] += c0;
        acc[t * 33 + (e1 & 31)] += a1;         acc[(t + 256) * 33 + (e1 & 31)] += c1;
        acc[t * 33 + (e2 & 31)] += a2;         acc[(t + 256) * 33 + (e2 & 31)] += c2;
        acc[t * 33 + (e3 & 31)] += a3;         acc[(t + 256) * 33 + (e3 & 31)] += c3;
    }
    for (; s < nq; ++s) {
        int e = q[s];
        float a0 = f[(size_t)(e >> 5) * K + t];
        float c0 = f[(size_t)(e >> 5) * K + t + 256];
        acc[t * 33 + (e & 31)] += a0;
        acc[(t + 256) * 33 + (e & 31)] += c0;
    }
    __syncthreads();
    for (int i = t; i < 512 * 32; i += 256) {   // fused EMA write-out
        int d = i >> 5, c = i & 31;
        size_t o = (size_t)d * M + b * 32 + c;
        o_avg[o] = 0.99f * ea[o] + 0.01f * acc[d * 33 + c];
    }
}

// ---------- new_cluster_size, n, cs ----------
__global__ __launch_bounds__(256) void k_cs(const float* __restrict__ cs_in,
                                            const float* __restrict__ counts,
                                            float* __restrict__ o_ncs,
                                            float* __restrict__ csr) {
    int tid = threadIdx.x;
    float myncs[32];
    float loc = 0.f;
#pragma unroll 32
    for (int i = 0; i < 32; ++i) {
        int j = i * 256 + tid;
        float v = 0.99f * cs_in[j] + 0.01f * counts[j];
        myncs[i] = v;
        o_ncs[j] = v;
        loc += v;
    }
#pragma unroll
    for (int off = 32; off; off >>= 1) loc += __shfl_down(loc, off);
    __shared__ float wsum[4];
    __shared__ float nsh;
    if ((tid & 63) == 0) wsum[tid >> 6] = loc;
    __syncthreads();
    if (tid == 0) nsh = wsum[0] + wsum[1] + wsum[2] + wsum[3];
    __syncthreads();
    float n = nsh;
#pragma unroll 32
    for (int i = 0; i < 32; ++i) {
        int j = i * 256 + tid;
        csr[j] = (myncs[i] + 1e-5f) / (n + 8192.0f * 1e-5f) * n;
    }
}

// ---------- new_embed = new_embed_avg / cs ----------
__global__ void k_div(const float* __restrict__ avg, const float* __restrict__ csr,
                      float* __restrict__ o_ne) {
    size_t idx = (size_t)blockIdx.x * 256 + threadIdx.x;
    size_t el = idx * 4;
    float4 a = *(const float4*)&avg[el];
    int j = (int)(el & (size_t)(M - 1));
    float4 cc = *(const float4*)&csr[j];
    float4 r;
    r.x = a.x / cc.x; r.y = a.y / cc.y; r.z = a.z / cc.z; r.w = a.w / cc.w;
    *(float4*)&o_ne[el] = r;
}

extern "C" void kernel_launch(void* const* d_in, const int* in_sizes, int n_in,
                              void* d_out, int out_size, void* d_ws, size_t ws_size,
                              hipStream_t stream) {
    const float* f     = (const float*)d_in[0];
    const float* E     = (const float*)d_in[1];
    const float* cs_in = (const float*)d_in[2];
    const float* ea    = (const float*)d_in[3];

    float* out = (float*)d_out;
    float* o_q    = out;                   // 4194304
    float* o_diff = out + 4194304;         // 1
    float* o_ind  = out + 4194305;         // 8192
    float* o_ne   = out + 4202497;         // 4194304
    float* o_ncs  = out + 8396801;         // 8192
    float* o_avg  = out + 8404993;         // 4194304

    // overlays (lifetimes audited):
    //   o_q  region: Fh (8 MB) — dead after k_score; k_gather then writes o_q
    //   o_ne region: EhT,ElT (16 MB) — read by score/combine/gather; k_div writes last
    //   o_avg region: pval,pidx (8 MB) — dead after k_combine; k_ema then writes o_avg
    ushortT* Fh  = (ushortT*)o_q;
    ushortT* EhT = (ushortT*)o_ne;
    ushortT* ElT = EhT + (size_t)M * K;
    float*   pval = o_avg;                       // [64][8192][2] floats
    int*     pidx = (int*)(o_avg + 1048576);     // [64][8192][2] ints

    float* wsf    = (float*)d_ws;
    float* c      = wsf;                   // 8192
    float* counts = wsf + 8192;            // 8192
    float* csr    = wsf + 16384;           // 8192
    int*   indws  = (int*)(wsf + 24576);   // 8192
    float* pc     = wsf + 32768;           // 8*8192

    k_prepF  <<<2048, 256, 0, stream>>>(f, Fh);
    k_prepE  <<<1024, 256, 0, stream>>>(E, EhT, ElT);
    k_cnorm  <<<256, 256, 0, stream>>>(E, pc);
    k_cfin   <<<32, 256, 0, stream>>>(pc, c, counts, o_diff);
    k_score  <<<4096, 256, 0, stream>>>(Fh, EhT, c, pval, pidx);
    k_combine<<<2048, 256, 0, stream>>>(pval, pidx, f, EhT, ElT, c, indws, o_ind, counts);
    k_gather <<<N, 64, 0, stream>>>(f, EhT, ElT, indws, o_q, o_diff);   // frees Fh region
    k_ema    <<<256, 256, 0, stream>>>(f, indws, ea, o_avg);            // frees pval/pidx
    k_cs     <<<1, 256, 0, stream>>>(cs_in, counts, o_ncs, csr);
    k_div    <<<4096, 256, 0, stream>>>(o_avg, csr, o_ne);              // overwrites EhT/ElT
}